// Round 7
// baseline (199.743 us; speedup 1.0000x reference)
//
#include <hip/hip_runtime.h>
#include <hip/hip_bf16.h>

#define BB 256      // batches
#define P 64        // cluster dim
#define MM 4096     // samples per row
#define MC 128      // chunk columns for cov staging
#define MTA 128     // tile columns for apply

using bf16x8 = __attribute__((ext_vector_type(8))) short;
using f32x16 = __attribute__((ext_vector_type(16))) float;

__device__ inline f32x16 MF(bf16x8 a, bf16x8 b, f32x16 c) {
    return __builtin_amdgcn_mfma_f32_32x32x16_bf16(a, b, c, 0, 0, 0);
}
__device__ inline unsigned cvtpk(float lo, float hi) {   // {bf16(lo), bf16(hi)} RTNE
    unsigned u;
    asm("v_cvt_pk_bf16_f32 %0, %1, %2" : "=v"(u) : "v"(lo), "v"(hi));
    return u;
}

// ---------------- Kernel A: pure-bf16 MFMA covariance partials ----------------
// grid (BB, nsplit), 256 thr. Double-buffered LDS: one barrier per chunk,
// chunk ch+1 global loads issue before the sync (fly under MFMA of ch).
__global__ __launch_bounds__(256)
void covpart_kernel(const float* __restrict__ x, float* __restrict__ s2p,
                    float* __restrict__ s1p, int nsplit)
{
    __shared__ __align__(16) unsigned char smem[34816];  // 2 x hi[64][136] bf16

    const int b = blockIdx.x, sp = blockIdx.y;
    const int t = threadIdx.x;
    const int w = t >> 6, l = t & 63;
    const int lr = l & 31, lh = l >> 5;
    const int mlen = MM / nsplit;
    const float* xb = x + (size_t)b * (P * MM) + (size_t)sp * mlen;

    f32x16 acc0 = {0,0,0,0,0,0,0,0,0,0,0,0,0,0,0,0};   // H00 partial
    f32x16 acc1 = {0,0,0,0,0,0,0,0,0,0,0,0,0,0,0,0};   // H01 partial
    f32x16 acc2 = {0,0,0,0,0,0,0,0,0,0,0,0,0,0,0,0};   // H11 partial
    float s1a[8] = {0.f,0.f,0.f,0.f,0.f,0.f,0.f,0.f};

    const int kbase = lh * 16;          // byte offset of lane's k-half in a slice
    const int nch = mlen / MC;

    float4 v[8];
    #pragma unroll
    for (int j = 0; j < 8; ++j) {
        int f4 = t + 256 * j;
        int r = f4 >> 5, c = (f4 & 31) << 2;
        v[j] = *reinterpret_cast<const float4*>(xb + (size_t)r * MM + c);
    }

    for (int ch = 0; ch < nch; ++ch) {
        char* buf = (char*)smem + (ch & 1) * 17408;
        #pragma unroll
        for (int j = 0; j < 8; ++j) {
            int f4 = t + 256 * j;
            int r = f4 >> 5, c4 = f4 & 31;
            float e0 = v[j].x, e1 = v[j].y, e2 = v[j].z, e3 = v[j].w;
            s1a[j] += (e0 + e1) + (e2 + e3);
            uint2 hp;
            hp.x = cvtpk(e0, e1);
            hp.y = cvtpk(e2, e3);
            *reinterpret_cast<uint2*>(buf + r * 272 + c4 * 8) = hp;
        }
        if (ch + 1 < nch) {
            const int m0 = (ch + 1) * MC;
            #pragma unroll
            for (int j = 0; j < 8; ++j) {
                int f4 = t + 256 * j;
                int r = f4 >> 5, c = (f4 & 31) << 2;
                v[j] = *reinterpret_cast<const float4*>(xb + (size_t)r * MM + m0 + c);
            }
        }
        __syncthreads();
        #pragma unroll
        for (int kk = 0; kk < 2; ++kk) {
            const int kb = (2 * w + kk) * 32 + kbase;
            bf16x8 f0 = *(const bf16x8*)(buf + lr * 272 + kb);
            bf16x8 f1 = *(const bf16x8*)(buf + (32 + lr) * 272 + kb);
            acc0 = MF(f0, f0, acc0);
            acc1 = MF(f0, f1, acc1);
            acc2 = MF(f1, f1, acc2);
        }
        // no trailing sync: next iter writes the other buffer; the barrier
        // above (with its lgkmcnt drain) fences writes(ch+2) vs reads(ch).
    }

    // ---- epilogue: cross-wave partial reduction via LDS, 3 passes ----
    float (*T)[32][33] = reinterpret_cast<float (*)[32][33]>(smem);  // 16.9 KB
    float* s2b = s2p + ((size_t)sp * BB + b) * (P * P);

#define REDUCE_PASS(ACC, STORE)                                       \
    {                                                                 \
        __syncthreads();                                              \
        _Pragma("unroll")                                             \
        for (int n = 0; n < 16; ++n) {                                \
            int row = (n & 3) + 8 * (n >> 2) + 4 * lh;                \
            T[w][row][lr] = ACC[n];                                   \
        }                                                             \
        __syncthreads();                                              \
        _Pragma("unroll")                                             \
        for (int q = 0; q < 4; ++q) {                                 \
            int idx = t + 256 * q;                                    \
            int r = idx >> 5, c = idx & 31;                           \
            float s = T[0][r][c] + T[1][r][c] + T[2][r][c] + T[3][r][c]; \
            STORE                                                     \
        }                                                             \
    }

    REDUCE_PASS(acc0, s2b[r * 64 + c] = s;)
    REDUCE_PASS(acc1, s2b[r * 64 + 32 + c] = s; s2b[(32 + c) * 64 + r] = s;)
    REDUCE_PASS(acc2, s2b[(32 + r) * 64 + 32 + c] = s;)
#undef REDUCE_PASS

    #pragma unroll
    for (int m = 16; m >= 1; m >>= 1) {
        #pragma unroll
        for (int j = 0; j < 8; ++j) s1a[j] += __shfl_xor(s1a[j], m);
    }
    if ((l & 31) == 0) {
        float* s1b = s1p + ((size_t)sp * BB + b) * P;
        int r0 = 2 * w + lh;
        #pragma unroll
        for (int j = 0; j < 8; ++j) s1b[r0 + 8 * j] = s1a[j];
    }
}

// ---------------- Kernel B: shrinkage + Newton-Schulz inverse sqrt ----------------
typedef float (*Mat68)[68];

__device__ inline void mm64f(Mat68 D, Mat68 A, Mat68 Bm, int t, float alpha, float beta)
{
    __syncthreads();
    const int r0 = (t >> 4) * 4, c0 = (t & 15) * 4;
    float acc[4][4];
    #pragma unroll
    for (int i = 0; i < 4; ++i)
        #pragma unroll
        for (int j = 0; j < 4; ++j) acc[i][j] = 0.f;
    #pragma unroll 4
    for (int k = 0; k < P; ++k) {
        float av[4], bv[4];
        *reinterpret_cast<float4*>(av) = *reinterpret_cast<const float4*>(&A[k][r0]);
        *reinterpret_cast<float4*>(bv) = *reinterpret_cast<const float4*>(&Bm[k][c0]);
        #pragma unroll
        for (int i = 0; i < 4; ++i)
            #pragma unroll
            for (int j = 0; j < 4; ++j) acc[i][j] += av[i] * bv[j];
    }
    __syncthreads();
    #pragma unroll
    for (int i = 0; i < 4; ++i)
        #pragma unroll
        for (int j = 0; j < 4; ++j)
            D[r0 + i][c0 + j] = alpha * acc[i][j] + ((r0 + i) == (c0 + j) ? beta : 0.f);
}

__global__ __launch_bounds__(256)
void whiten_kernel(const float* __restrict__ s2p, const float* __restrict__ s1p,
                   unsigned* __restrict__ sbb, float* __restrict__ tvec, int nsplit)
{
    __shared__ __align__(16) float B0[P][68], B1[P][68], B2[P][68], B3[P][68], B4[P][68];
    __shared__ float mus[P];
    __shared__ float red[2][4];
    const int b = blockIdx.x, t = threadIdx.x;

    if (t < P) {
        float s = 0.f;
        for (int sp = 0; sp < nsplit; ++sp) s += s1p[((size_t)sp * BB + b) * P + t];
        mus[t] = s * (1.0f / MM);
    }
    __syncthreads();

    float tr_part = 0.f, s2_part = 0.f;
    #pragma unroll
    for (int j = 0; j < 16; ++j) {
        int f = t + 256 * j;
        int i = f >> 6, jc = f & 63;
        float sum = 0.f;
        for (int sp = 0; sp < nsplit; ++sp)
            sum += s2p[((size_t)sp * BB + b) * (P * P) + f];
        float v = sum * (1.0f / MM) - mus[i] * mus[jc];
        B0[i][jc] = v;
        s2_part += v * v;
        if (i == jc) tr_part += v;
    }
    #pragma unroll
    for (int off = 32; off > 0; off >>= 1) {
        tr_part += __shfl_down(tr_part, off);
        s2_part += __shfl_down(s2_part, off);
    }
    if ((t & 63) == 0) { red[0][t >> 6] = tr_part; red[1][t >> 6] = s2_part; }
    __syncthreads();
    const float trace = red[0][0] + red[0][1] + red[0][2] + red[0][3];
    const float sum2  = red[1][0] + red[1][1] + red[1][2] + red[1][3];

    const float nf = (float)MM;
    const float num = (nf - 2.0f) / nf * sum2 + trace * trace;
    const float den = (nf + 2.0f) * (sum2 - trace * trace / (float)P);
    const float rho = (den > 0.f) ? fminf(num / den, 1.0f) : 1.0f;
    const float lam = trace * (1.0f / P);
    const float inv_s = 1.0f / lam;

    #pragma unroll
    for (int j = 0; j < 16; ++j) {
        int f = t + 256 * j;
        int i = f >> 6, jc = f & 63;
        float v = B0[i][jc];
        float sv = ((1.0f - rho) * v + ((i == jc) ? rho * lam : 0.f)) * inv_s;
        B0[i][jc] = sv;
        B2[i][jc] = ((i == jc) ? 1.5f : 0.f) - 0.5f * sv;
    }

    // Newton-Schulz, 3 maps (spectrum in [0.73,1.27] -> error ~6e-6)
    mm64f(B1, B0, B2, t, 1.f, 0.f);          // map1: Y1=A*T1, Z1=T1
    Mat68 Yc = B1, Zc = B2, Tc = B0, U = B3, V = B4;
    {
        mm64f(Tc, Zc, Yc, t, -0.5f, 1.5f);   // map2
        mm64f(U,  Yc, Tc, t, 1.f, 0.f);
        mm64f(V,  Tc, Zc, t, 1.f, 0.f);
        Mat68 tmp = Yc; Yc = U; U = tmp;
        tmp = Zc; Zc = V; V = tmp;
    }
    mm64f(Tc, Zc, Yc, t, -0.5f, 1.5f);       // map3
    mm64f(U,  Tc, Zc, t, 1.f, 0.f);          // U = A^{-1/2}
    __syncthreads();

    const float sc = rsqrtf(lam);
    // S_hat emitted in apply's pair-packed layout: sbpk[dp*64 + row] =
    // {bf16 S[row][2dp], bf16 S[row][2dp+1]} (S symmetric). Coalesced slots.
    unsigned* sb = sbb + (size_t)b * (P * P / 2);
    #pragma unroll
    for (int j = 0; j < 8; ++j) {
        int slot = t + 256 * j;
        int dp = slot >> 6, row = slot & 63;
        sb[slot] = cvtpk(U[row][2 * dp] * sc, U[row][2 * dp + 1] * sc);
    }
    if (t < P) {
        float tv = 0.f;
        #pragma unroll
        for (int d = 0; d < P; ++d) tv += U[t][d] * mus[d];
        tvec[b * P + t] = tv * sc;
    }
}

// ---------------- Kernel C: Z = S_hat * x - (S_hat mu), MFMA ----------------
// Both operands pair-packed along d: Spk[dp][row], Xpk[dp][m]. All fragment
// reads are 4x b32 at bank = row/m + const -> conflict-free. ~26 KB LDS ->
// 6 blocks/CU.
__global__ __launch_bounds__(256)
void apply_kernel(const float* __restrict__ x, const unsigned* __restrict__ sbb,
                  const float* __restrict__ tvec, float* __restrict__ out)
{
    __shared__ unsigned Spk[32][68];     // 8704 B
    __shared__ unsigned Xpk[32][132];    // 16896 B
    __shared__ float tvs[P];
    const int mt = blockIdx.x, b = blockIdx.y;
    const int t = threadIdx.x;
    const int w = t >> 6, l = t & 63;
    const int lr = l & 31, lh = l >> 5;

    const unsigned* sb = sbb + (size_t)b * (P * P / 2);
    #pragma unroll
    for (int j = 0; j < 8; ++j) {
        int slot = t + 256 * j;
        Spk[slot >> 6][slot & 63] = sb[slot];
    }
    if (t < P) tvs[t] = tvec[b * P + t];

    const float* xb = x + (size_t)b * (P * MM) + mt * MTA;
    #pragma unroll
    for (int j = 0; j < 4; ++j) {
        int slot = t + 256 * j;
        int dp = slot >> 5, m0 = (slot & 31) * 4;
        const float* xr = xb + (size_t)(2 * dp) * MM + m0;
        float4 a = *reinterpret_cast<const float4*>(xr);
        float4 c = *reinterpret_cast<const float4*>(xr + MM);
        uint4 pk = make_uint4(cvtpk(a.x, c.x), cvtpk(a.y, c.y),
                              cvtpk(a.z, c.z), cvtpk(a.w, c.w));
        *reinterpret_cast<uint4*>(&Xpk[dp][m0]) = pk;
    }
    __syncthreads();

    f32x16 acc0 = {0,0,0,0,0,0,0,0,0,0,0,0,0,0,0,0};   // rows 0..31
    f32x16 acc1 = {0,0,0,0,0,0,0,0,0,0,0,0,0,0,0,0};   // rows 32..63
    const int cq = w * 32 + lr;
    #pragma unroll
    for (int ks = 0; ks < 4; ++ks) {
        const int dpb = ks * 8 + lh * 4;
        union { unsigned u[4]; bf16x8 v; } a0, a1, bb;
        #pragma unroll
        for (int q = 0; q < 4; ++q) {
            a0.u[q] = Spk[dpb + q][lr];
            a1.u[q] = Spk[dpb + q][32 + lr];
            bb.u[q] = Xpk[dpb + q][cq];
        }
        acc0 = MF(a0.v, bb.v, acc0);
        acc1 = MF(a1.v, bb.v, acc1);
    }

    float* ob = out + (size_t)b * (P * MM) + mt * MTA;
    #pragma unroll
    for (int n = 0; n < 16; ++n) {
        int r0 = (n & 3) + 8 * (n >> 2) + 4 * lh;
        ob[(size_t)r0 * MM + cq]        = acc0[n] - tvs[r0];
        ob[(size_t)(32 + r0) * MM + cq] = acc1[n] - tvs[32 + r0];
    }
}

extern "C" void kernel_launch(void* const* d_in, const int* in_sizes, int n_in,
                              void* d_out, int out_size, void* d_ws, size_t ws_size,
                              hipStream_t stream)
{
    const float* x = (const float*)d_in[0];
    float* out = (float*)d_out;

    // scratch: s2p[ns][B][64][64] f32 | s1p[ns][B][64] f32 |
    // sbb[B][32][64] uint bf16-pairs | tvec[B][64] f32
    auto need = [](int ns) -> size_t {
        return ((size_t)ns * BB * P * P + (size_t)ns * BB * P
                + (size_t)BB * P * P / 2 + (size_t)BB * P) * sizeof(float);
    };
    int nsplit = 4;
    if (ws_size < need(4)) nsplit = 2;
    if (ws_size < need(2)) nsplit = 1;

    float* s2p  = (float*)d_ws;
    float* s1p  = s2p + (size_t)nsplit * BB * P * P;
    unsigned* sbb = (unsigned*)(s1p + (size_t)nsplit * BB * P);
    float* tvec = (float*)(sbb + (size_t)BB * P * P / 2);

    covpart_kernel<<<dim3(BB, nsplit), 256, 0, stream>>>(x, s2p, s1p, nsplit);
    whiten_kernel<<<dim3(BB), 256, 0, stream>>>(s2p, s1p, sbb, tvec, nsplit);
    apply_kernel<<<dim3(MM / MTA, BB), 256, 0, stream>>>(x, sbb, tvec, out);
}

// Round 10
// 196.196 us; speedup vs baseline: 1.0181x; 1.0181x over previous
//
#include <hip/hip_runtime.h>
#include <hip/hip_bf16.h>

#define BB 256      // batches
#define P 64        // cluster dim
#define MM 4096     // samples per row
#define MC 128      // chunk columns for cov staging
#define MT 256      // tile columns for apply

using bf16x8 = __attribute__((ext_vector_type(8))) short;
using f32x16 = __attribute__((ext_vector_type(16))) float;
using f32x4  = __attribute__((ext_vector_type(4))) float;   // native vec for nontemporal builtins

__device__ inline f32x16 MF(bf16x8 a, bf16x8 b, f32x16 c) {
    return __builtin_amdgcn_mfma_f32_32x32x16_bf16(a, b, c, 0, 0, 0);
}
__device__ inline unsigned cvtpk(float lo, float hi) {   // {bf16(lo), bf16(hi)} RTNE
    unsigned u;
    asm("v_cvt_pk_bf16_f32 %0, %1, %2" : "=v"(u) : "v"(lo), "v"(hi));
    return u;
}

// ---------------- Kernel A: pure-bf16 MFMA covariance partials ----------------
// grid (BB, nsplit), 256 thr. Double-buffered LDS: one barrier per chunk;
// barrier(ch) both publishes writes(ch) and (via its lgkmcnt drain) proves
// all reads(ch-1) landed, so writes(ch+1) into the other buffer are safe.
__global__ __launch_bounds__(256)
void covpart_kernel(const float* __restrict__ x, float* __restrict__ s2p,
                    float* __restrict__ s1p, int nsplit)
{
    __shared__ __align__(16) unsigned char smem[34816];  // 2 x hi[64][136] bf16

    const int b = blockIdx.x, sp = blockIdx.y;
    const int t = threadIdx.x;
    const int w = t >> 6, l = t & 63;
    const int lr = l & 31, lh = l >> 5;
    const int mlen = MM / nsplit;
    const float* xb = x + (size_t)b * (P * MM) + (size_t)sp * mlen;

    f32x16 acc0 = {0,0,0,0,0,0,0,0,0,0,0,0,0,0,0,0};   // H00 partial
    f32x16 acc1 = {0,0,0,0,0,0,0,0,0,0,0,0,0,0,0,0};   // H01 partial
    f32x16 acc2 = {0,0,0,0,0,0,0,0,0,0,0,0,0,0,0,0};   // H11 partial
    float s1a[8] = {0.f,0.f,0.f,0.f,0.f,0.f,0.f,0.f};

    const int kbase = lh * 16;          // byte offset of lane's k-half in a slice
    const int nch = mlen / MC;

    f32x4 v[8];
    #pragma unroll
    for (int j = 0; j < 8; ++j) {
        int f4 = t + 256 * j;
        int r = f4 >> 5, c = (f4 & 31) << 2;
        v[j] = *reinterpret_cast<const f32x4*>(xb + (size_t)r * MM + c);
    }

    for (int ch = 0; ch < nch; ++ch) {
        char* buf = (char*)smem + (ch & 1) * 17408;
        #pragma unroll
        for (int j = 0; j < 8; ++j) {
            int f4 = t + 256 * j;
            int r = f4 >> 5, c4 = f4 & 31;
            float e0 = v[j].x, e1 = v[j].y, e2 = v[j].z, e3 = v[j].w;
            s1a[j] += (e0 + e1) + (e2 + e3);
            uint2 hp;
            hp.x = cvtpk(e0, e1);
            hp.y = cvtpk(e2, e3);
            *reinterpret_cast<uint2*>(buf + r * 272 + c4 * 8) = hp;
        }
        if (ch + 1 < nch) {
            const int m0 = (ch + 1) * MC;
            #pragma unroll
            for (int j = 0; j < 8; ++j) {
                int f4 = t + 256 * j;
                int r = f4 >> 5, c = (f4 & 31) << 2;
                v[j] = *reinterpret_cast<const f32x4*>(xb + (size_t)r * MM + m0 + c);
            }
        }
        __syncthreads();
        #pragma unroll
        for (int kk = 0; kk < 2; ++kk) {
            const int kb = (2 * w + kk) * 32 + kbase;
            bf16x8 f0 = *(const bf16x8*)(buf + lr * 272 + kb);
            bf16x8 f1 = *(const bf16x8*)(buf + (32 + lr) * 272 + kb);
            acc0 = MF(f0, f0, acc0);
            acc1 = MF(f0, f1, acc1);
            acc2 = MF(f1, f1, acc2);
        }
    }

    // ---- epilogue: cross-wave partial reduction via LDS, 3 passes ----
    float (*T)[32][33] = reinterpret_cast<float (*)[32][33]>(smem);  // 16.9 KB
    float* s2b = s2p + ((size_t)sp * BB + b) * (P * P);

#define REDUCE_PASS(ACC, STORE)                                       \
    {                                                                 \
        __syncthreads();                                              \
        _Pragma("unroll")                                             \
        for (int n = 0; n < 16; ++n) {                                \
            int row = (n & 3) + 8 * (n >> 2) + 4 * lh;                \
            T[w][row][lr] = ACC[n];                                   \
        }                                                             \
        __syncthreads();                                              \
        _Pragma("unroll")                                             \
        for (int q = 0; q < 4; ++q) {                                 \
            int idx = t + 256 * q;                                    \
            int r = idx >> 5, c = idx & 31;                           \
            float s = T[0][r][c] + T[1][r][c] + T[2][r][c] + T[3][r][c]; \
            STORE                                                     \
        }                                                             \
    }

    REDUCE_PASS(acc0, s2b[r * 64 + c] = s;)
    REDUCE_PASS(acc1, s2b[r * 64 + 32 + c] = s; s2b[(32 + c) * 64 + r] = s;)
    REDUCE_PASS(acc2, s2b[(32 + r) * 64 + 32 + c] = s;)
#undef REDUCE_PASS

    #pragma unroll
    for (int m = 16; m >= 1; m >>= 1) {
        #pragma unroll
        for (int j = 0; j < 8; ++j) s1a[j] += __shfl_xor(s1a[j], m);
    }
    if ((l & 31) == 0) {
        float* s1b = s1p + ((size_t)sp * BB + b) * P;
        int r0 = 2 * w + lh;
        #pragma unroll
        for (int j = 0; j < 8; ++j) s1b[r0 + 8 * j] = s1a[j];
    }
}

// ---------------- Kernel B: shrinkage + Newton-Schulz inverse sqrt ----------------
typedef float (*Mat68)[68];

__device__ inline void mm64f(Mat68 D, Mat68 A, Mat68 Bm, int t, float alpha, float beta)
{
    __syncthreads();
    const int r0 = (t >> 4) * 4, c0 = (t & 15) * 4;
    float acc[4][4];
    #pragma unroll
    for (int i = 0; i < 4; ++i)
        #pragma unroll
        for (int j = 0; j < 4; ++j) acc[i][j] = 0.f;
    #pragma unroll 4
    for (int k = 0; k < P; ++k) {
        float av[4], bv[4];
        *reinterpret_cast<float4*>(av) = *reinterpret_cast<const float4*>(&A[k][r0]);
        *reinterpret_cast<float4*>(bv) = *reinterpret_cast<const float4*>(&Bm[k][c0]);
        #pragma unroll
        for (int i = 0; i < 4; ++i)
            #pragma unroll
            for (int j = 0; j < 4; ++j) acc[i][j] += av[i] * bv[j];
    }
    __syncthreads();
    #pragma unroll
    for (int i = 0; i < 4; ++i)
        #pragma unroll
        for (int j = 0; j < 4; ++j)
            D[r0 + i][c0 + j] = alpha * acc[i][j] + ((r0 + i) == (c0 + j) ? beta : 0.f);
}

__global__ __launch_bounds__(256)
void whiten_kernel(const float* __restrict__ s2p, const float* __restrict__ s1p,
                   unsigned* __restrict__ sbb, float* __restrict__ tvec, int nsplit)
{
    __shared__ __align__(16) float B0[P][68], B1[P][68], B2[P][68], B3[P][68], B4[P][68];
    __shared__ float mus[P];
    __shared__ float red[2][4];
    const int b = blockIdx.x, t = threadIdx.x;

    if (t < P) {
        float s = 0.f;
        for (int sp = 0; sp < nsplit; ++sp) s += s1p[((size_t)sp * BB + b) * P + t];
        mus[t] = s * (1.0f / MM);
    }
    __syncthreads();

    float tr_part = 0.f, s2_part = 0.f;
    #pragma unroll
    for (int j = 0; j < 16; ++j) {
        int f = t + 256 * j;
        int i = f >> 6, jc = f & 63;
        float sum = 0.f;
        for (int sp = 0; sp < nsplit; ++sp)
            sum += s2p[((size_t)sp * BB + b) * (P * P) + f];
        float v = sum * (1.0f / MM) - mus[i] * mus[jc];
        B0[i][jc] = v;
        s2_part += v * v;
        if (i == jc) tr_part += v;
    }
    #pragma unroll
    for (int off = 32; off > 0; off >>= 1) {
        tr_part += __shfl_down(tr_part, off);
        s2_part += __shfl_down(s2_part, off);
    }
    if ((t & 63) == 0) { red[0][t >> 6] = tr_part; red[1][t >> 6] = s2_part; }
    __syncthreads();
    const float trace = red[0][0] + red[0][1] + red[0][2] + red[0][3];
    const float sum2  = red[1][0] + red[1][1] + red[1][2] + red[1][3];

    const float nf = (float)MM;
    const float num = (nf - 2.0f) / nf * sum2 + trace * trace;
    const float den = (nf + 2.0f) * (sum2 - trace * trace / (float)P);
    const float rho = (den > 0.f) ? fminf(num / den, 1.0f) : 1.0f;
    const float lam = trace * (1.0f / P);
    const float inv_s = 1.0f / lam;

    #pragma unroll
    for (int j = 0; j < 16; ++j) {
        int f = t + 256 * j;
        int i = f >> 6, jc = f & 63;
        float v = B0[i][jc];
        float sv = ((1.0f - rho) * v + ((i == jc) ? rho * lam : 0.f)) * inv_s;
        B0[i][jc] = sv;
        B2[i][jc] = ((i == jc) ? 1.5f : 0.f) - 0.5f * sv;
    }

    // Newton-Schulz, 3 maps (spectrum in [0.73,1.27] -> error ~6e-6)
    mm64f(B1, B0, B2, t, 1.f, 0.f);          // map1: Y1=A*T1, Z1=T1
    Mat68 Yc = B1, Zc = B2, Tc = B0, U = B3, V = B4;
    {
        mm64f(Tc, Zc, Yc, t, -0.5f, 1.5f);   // map2
        mm64f(U,  Yc, Tc, t, 1.f, 0.f);
        mm64f(V,  Tc, Zc, t, 1.f, 0.f);
        Mat68 tmp = Yc; Yc = U; U = tmp;
        tmp = Zc; Zc = V; V = tmp;
    }
    mm64f(Tc, Zc, Yc, t, -0.5f, 1.5f);       // map3
    mm64f(U,  Tc, Zc, t, 1.f, 0.f);          // U = A^{-1/2}
    __syncthreads();

    const float sc = rsqrtf(lam);
    // S_hat emitted pair-packed: sb[dp*64 + row] = {bf16 S[row][2dp], bf16 S[row][2dp+1]}
    unsigned* sb = sbb + (size_t)b * (P * P / 2);
    #pragma unroll
    for (int j = 0; j < 8; ++j) {
        int slot = t + 256 * j;
        int dp = slot >> 6, row = slot & 63;
        sb[slot] = cvtpk(U[row][2 * dp] * sc, U[row][2 * dp + 1] * sc);
    }
    if (t < P) {
        float tv = 0.f;
        #pragma unroll
        for (int d = 0; d < P; ++d) tv += U[t][d] * mus[d];
        tvec[b * P + t] = tv * sc;
    }
}

// ---------------- Kernel C: Z = S_hat * x - (S_hat mu), MFMA ----------------
// MT=256 tile. Spk[dp][row] and Xpk[dp][m] pair-packed along d: all fragment
// reads are b32 gathers at bank (4dp + lane) -> conflict-free. x loads are
// nontemporal (hit L3 if resident, don't re-pollute); out stores nontemporal
// (streaming write-once must not evict x from L3).
__global__ __launch_bounds__(256)
void apply_kernel(const float* __restrict__ x, const unsigned* __restrict__ sbb,
                  const float* __restrict__ tvec, float* __restrict__ out)
{
    __shared__ unsigned Spk[32][68];     // 8704 B
    __shared__ unsigned Xpk[32][260];    // 33280 B
    __shared__ float tvs[P];
    const int mt = blockIdx.x, b = blockIdx.y;
    const int t = threadIdx.x;
    const int w = t >> 6, l = t & 63;
    const int lr = l & 31, lh = l >> 5;

    const unsigned* sb = sbb + (size_t)b * (P * P / 2);
    #pragma unroll
    for (int j = 0; j < 8; ++j) {
        int slot = t + 256 * j;
        Spk[slot >> 6][slot & 63] = sb[slot];
    }
    if (t < P) tvs[t] = tvec[b * P + t];

    const float* xb = x + (size_t)b * (P * MM) + mt * MT;
    #pragma unroll
    for (int j = 0; j < 8; ++j) {
        int slot = t + 256 * j;
        int dp = slot >> 6, m0 = (slot & 63) * 4;
        const float* xr = xb + (size_t)(2 * dp) * MM + m0;
        f32x4 a = __builtin_nontemporal_load(reinterpret_cast<const f32x4*>(xr));
        f32x4 c = __builtin_nontemporal_load(reinterpret_cast<const f32x4*>(xr + MM));
        uint4 pk = make_uint4(cvtpk(a.x, c.x), cvtpk(a.y, c.y),
                              cvtpk(a.z, c.z), cvtpk(a.w, c.w));
        *reinterpret_cast<uint4*>(&Xpk[dp][m0]) = pk;
    }
    __syncthreads();

    // hoist S fragments to registers (b32 conflict-free gathers)
    union U8 { unsigned u[4]; bf16x8 v; };
    bf16x8 sa0[4], sa1[4];
    #pragma unroll
    for (int ks = 0; ks < 4; ++ks) {
        const int dpb = ks * 8 + lh * 4;
        U8 x0, x1;
        #pragma unroll
        for (int q = 0; q < 4; ++q) {
            x0.u[q] = Spk[dpb + q][lr];
            x1.u[q] = Spk[dpb + q][32 + lr];
        }
        sa0[ks] = x0.v;
        sa1[ks] = x1.v;
    }

    f32x16 acc00 = {0,0,0,0,0,0,0,0,0,0,0,0,0,0,0,0};
    f32x16 acc01 = {0,0,0,0,0,0,0,0,0,0,0,0,0,0,0,0};
    f32x16 acc10 = {0,0,0,0,0,0,0,0,0,0,0,0,0,0,0,0};
    f32x16 acc11 = {0,0,0,0,0,0,0,0,0,0,0,0,0,0,0,0};

    const int cq0 = (2 * w) * 32 + lr, cq1 = cq0 + 32;
    #pragma unroll
    for (int ks = 0; ks < 4; ++ks) {
        const int dpb = ks * 8 + lh * 4;
        U8 b0, b1;
        #pragma unroll
        for (int q = 0; q < 4; ++q) {
            b0.u[q] = Xpk[dpb + q][cq0];
            b1.u[q] = Xpk[dpb + q][cq1];
        }
        acc00 = MF(sa0[ks], b0.v, acc00);
        acc01 = MF(sa0[ks], b1.v, acc01);
        acc10 = MF(sa1[ks], b0.v, acc10);
        acc11 = MF(sa1[ks], b1.v, acc11);
    }

    float* ob = out + (size_t)b * (P * MM) + mt * MT;
#define STORE_TILE(ACC, RT, CQ)                                          \
    {                                                                    \
        _Pragma("unroll")                                                \
        for (int n = 0; n < 16; ++n) {                                   \
            int row = (RT) * 32 + (n & 3) + 8 * (n >> 2) + 4 * lh;       \
            __builtin_nontemporal_store(ACC[n] - tvs[row],               \
                                        ob + (size_t)row * MM + (CQ));   \
        }                                                                \
    }
    STORE_TILE(acc00, 0, cq0)
    STORE_TILE(acc01, 0, cq1)
    STORE_TILE(acc10, 1, cq0)
    STORE_TILE(acc11, 1, cq1)
#undef STORE_TILE
}

extern "C" void kernel_launch(void* const* d_in, const int* in_sizes, int n_in,
                              void* d_out, int out_size, void* d_ws, size_t ws_size,
                              hipStream_t stream)
{
    const float* x = (const float*)d_in[0];
    float* out = (float*)d_out;

    // scratch: s2p[ns][B][64][64] f32 | s1p[ns][B][64] f32 |
    // sbb[B][32][64] uint bf16-pairs | tvec[B][64] f32
    auto need = [](int ns) -> size_t {
        return ((size_t)ns * BB * P * P + (size_t)ns * BB * P
                + (size_t)BB * P * P / 2 + (size_t)BB * P) * sizeof(float);
    };
    int nsplit = 4;
    if (ws_size < need(4)) nsplit = 2;
    if (ws_size < need(2)) nsplit = 1;

    float* s2p  = (float*)d_ws;
    float* s1p  = s2p + (size_t)nsplit * BB * P * P;
    unsigned* sbb = (unsigned*)(s1p + (size_t)nsplit * BB * P);
    float* tvec = (float*)(sbb + (size_t)BB * P * P / 2);

    covpart_kernel<<<dim3(BB, nsplit), 256, 0, stream>>>(x, s2p, s1p, nsplit);
    whiten_kernel<<<dim3(BB), 256, 0, stream>>>(s2p, s1p, sbb, tvec, nsplit);
    apply_kernel<<<dim3(MM / MT, BB), 256, 0, stream>>>(x, sbb, tvec, out);
}

// Round 11
// 186.983 us; speedup vs baseline: 1.0682x; 1.0493x over previous
//
#include <hip/hip_runtime.h>
#include <hip/hip_bf16.h>

#define BB 256      // batches
#define P 64        // cluster dim
#define MM 4096     // samples per row
#define MC 128      // chunk columns for cov staging
#define MT 256      // tile columns for apply

using bf16x8 = __attribute__((ext_vector_type(8))) short;
using f32x16 = __attribute__((ext_vector_type(16))) float;
using f32x4  = __attribute__((ext_vector_type(4))) float;
using u32x4  = __attribute__((ext_vector_type(4))) unsigned;
using u32x2  = __attribute__((ext_vector_type(2))) unsigned;

__device__ inline f32x16 MF(bf16x8 a, bf16x8 b, f32x16 c) {
    return __builtin_amdgcn_mfma_f32_32x32x16_bf16(a, b, c, 0, 0, 0);
}
__device__ inline unsigned cvtpk(float lo, float hi) {   // {bf16(lo), bf16(hi)} RTNE
    unsigned u;
    asm("v_cvt_pk_bf16_f32 %0, %1, %2" : "=v"(u) : "v"(lo), "v"(hi));
    return u;
}

// ---------------- Kernel A: pure-bf16 MFMA covariance partials ----------------
// grid (BB, nsplit), 256 thr, double-buffered LDS (1 barrier/chunk).
// Each thread stages a row-PAIR (rows 2dp, 2dp+1): m-packed pairs go to the
// LDS tile for the cov MFMA; if XPK, d-packed pairs (apply's B layout) are
// also streamed to global xpk[b][dp][m] -- bit-identical bf16, so apply's
// numerics are unchanged while its read traffic halves.
template<bool XPK>
__global__ __launch_bounds__(256)
void covpart_kernel(const float* __restrict__ x, float* __restrict__ s2p,
                    float* __restrict__ s1p, unsigned* __restrict__ xpk, int nsplit)
{
    __shared__ __align__(16) unsigned char smem[34816];  // 2 x hi[64][136] bf16

    const int b = blockIdx.x, sp = blockIdx.y;
    const int t = threadIdx.x;
    const int w = t >> 6, l = t & 63;
    const int lr = l & 31, lh = l >> 5;
    const int mlen = MM / nsplit;
    const float* xb = x + (size_t)b * (P * MM) + (size_t)sp * mlen;
    unsigned* xpb = XPK ? (xpk + (size_t)b * (32 * MM) + (size_t)sp * mlen) : nullptr;

    f32x16 acc0 = {0,0,0,0,0,0,0,0,0,0,0,0,0,0,0,0};   // H00 partial
    f32x16 acc1 = {0,0,0,0,0,0,0,0,0,0,0,0,0,0,0,0};   // H01 partial
    f32x16 acc2 = {0,0,0,0,0,0,0,0,0,0,0,0,0,0,0,0};   // H11 partial
    float s1e[4] = {0.f,0.f,0.f,0.f};
    float s1o[4] = {0.f,0.f,0.f,0.f};

    const int kbase = lh * 16;          // byte offset of lane's k-half in a slice
    const int nch = mlen / MC;

    f32x4 ve[4], vo[4];
    #pragma unroll
    for (int j = 0; j < 4; ++j) {
        int slot = t + 256 * j;
        int dp = slot >> 5, c = (slot & 31) << 2;
        const float* p = xb + (size_t)(2 * dp) * MM + c;
        ve[j] = *reinterpret_cast<const f32x4*>(p);
        vo[j] = *reinterpret_cast<const f32x4*>(p + MM);
    }

    for (int ch = 0; ch < nch; ++ch) {
        char* buf = (char*)smem + (ch & 1) * 17408;
        #pragma unroll
        for (int j = 0; j < 4; ++j) {
            int slot = t + 256 * j;
            int dp = slot >> 5, c4 = slot & 31;
            float e0 = ve[j].x, e1 = ve[j].y, e2 = ve[j].z, e3 = ve[j].w;
            float o0 = vo[j].x, o1 = vo[j].y, o2 = vo[j].z, o3 = vo[j].w;
            s1e[j] += (e0 + e1) + (e2 + e3);
            s1o[j] += (o0 + o1) + (o2 + o3);
            u32x2 he, ho;
            he.x = cvtpk(e0, e1); he.y = cvtpk(e2, e3);
            ho.x = cvtpk(o0, o1); ho.y = cvtpk(o2, o3);
            char* dst = buf + (2 * dp) * 272 + c4 * 8;
            *reinterpret_cast<u32x2*>(dst) = he;
            *reinterpret_cast<u32x2*>(dst + 272) = ho;
            if (XPK) {
                u32x4 pd;
                pd.x = cvtpk(e0, o0); pd.y = cvtpk(e1, o1);
                pd.z = cvtpk(e2, o2); pd.w = cvtpk(e3, o3);
                *reinterpret_cast<u32x4*>(xpb + (size_t)dp * MM + ch * MC + c4 * 4) = pd;
            }
        }
        if (ch + 1 < nch) {
            const int m0 = (ch + 1) * MC;
            #pragma unroll
            for (int j = 0; j < 4; ++j) {
                int slot = t + 256 * j;
                int dp = slot >> 5, c = (slot & 31) << 2;
                const float* p = xb + (size_t)(2 * dp) * MM + m0 + c;
                ve[j] = *reinterpret_cast<const f32x4*>(p);
                vo[j] = *reinterpret_cast<const f32x4*>(p + MM);
            }
        }
        __syncthreads();
        #pragma unroll
        for (int kk = 0; kk < 2; ++kk) {
            const int kb = (2 * w + kk) * 32 + kbase;
            bf16x8 f0 = *(const bf16x8*)(buf + lr * 272 + kb);
            bf16x8 f1 = *(const bf16x8*)(buf + (32 + lr) * 272 + kb);
            acc0 = MF(f0, f0, acc0);
            acc1 = MF(f0, f1, acc1);
            acc2 = MF(f1, f1, acc2);
        }
    }

    // ---- epilogue: cross-wave partial reduction via LDS, 3 passes ----
    float (*T)[32][33] = reinterpret_cast<float (*)[32][33]>(smem);  // 16.9 KB
    float* s2b = s2p + ((size_t)sp * BB + b) * (P * P);

#define REDUCE_PASS(ACC, STORE)                                       \
    {                                                                 \
        __syncthreads();                                              \
        _Pragma("unroll")                                             \
        for (int n = 0; n < 16; ++n) {                                \
            int row = (n & 3) + 8 * (n >> 2) + 4 * lh;                \
            T[w][row][lr] = ACC[n];                                   \
        }                                                             \
        __syncthreads();                                              \
        _Pragma("unroll")                                             \
        for (int q = 0; q < 4; ++q) {                                 \
            int idx = t + 256 * q;                                    \
            int r = idx >> 5, c = idx & 31;                           \
            float s = T[0][r][c] + T[1][r][c] + T[2][r][c] + T[3][r][c]; \
            STORE                                                     \
        }                                                             \
    }

    REDUCE_PASS(acc0, s2b[r * 64 + c] = s;)
    REDUCE_PASS(acc1, s2b[r * 64 + 32 + c] = s; s2b[(32 + c) * 64 + r] = s;)
    REDUCE_PASS(acc2, s2b[(32 + r) * 64 + 32 + c] = s;)
#undef REDUCE_PASS

    // ---- s1 row sums: each 32-lane group shares a row pair per j ----
    #pragma unroll
    for (int m = 16; m >= 1; m >>= 1) {
        #pragma unroll
        for (int j = 0; j < 4; ++j) {
            s1e[j] += __shfl_xor(s1e[j], m);
            s1o[j] += __shfl_xor(s1o[j], m);
        }
    }
    if ((t & 31) == 0) {
        float* s1b = s1p + ((size_t)sp * BB + b) * P;
        int g = t >> 5;                 // 0..7
        #pragma unroll
        for (int j = 0; j < 4; ++j) {
            int r0 = 2 * (g + 8 * j);
            s1b[r0]     = s1e[j];
            s1b[r0 + 1] = s1o[j];
        }
    }
}

// ---------------- Kernel B: shrinkage + Newton-Schulz inverse sqrt ----------------
typedef float (*Mat68)[68];

__device__ inline void mm64f(Mat68 D, Mat68 A, Mat68 Bm, int t, float alpha, float beta)
{
    __syncthreads();
    const int r0 = (t >> 4) * 4, c0 = (t & 15) * 4;
    float acc[4][4];
    #pragma unroll
    for (int i = 0; i < 4; ++i)
        #pragma unroll
        for (int j = 0; j < 4; ++j) acc[i][j] = 0.f;
    #pragma unroll 4
    for (int k = 0; k < P; ++k) {
        float av[4], bv[4];
        *reinterpret_cast<float4*>(av) = *reinterpret_cast<const float4*>(&A[k][r0]);
        *reinterpret_cast<float4*>(bv) = *reinterpret_cast<const float4*>(&Bm[k][c0]);
        #pragma unroll
        for (int i = 0; i < 4; ++i)
            #pragma unroll
            for (int j = 0; j < 4; ++j) acc[i][j] += av[i] * bv[j];
    }
    __syncthreads();
    #pragma unroll
    for (int i = 0; i < 4; ++i)
        #pragma unroll
        for (int j = 0; j < 4; ++j)
            D[r0 + i][c0 + j] = alpha * acc[i][j] + ((r0 + i) == (c0 + j) ? beta : 0.f);
}

__global__ __launch_bounds__(256)
void whiten_kernel(const float* __restrict__ s2p, const float* __restrict__ s1p,
                   unsigned* __restrict__ sbb, float* __restrict__ tvec, int nsplit)
{
    __shared__ __align__(16) float B0[P][68], B1[P][68], B2[P][68], B3[P][68], B4[P][68];
    __shared__ float mus[P];
    __shared__ float red[2][4];
    const int b = blockIdx.x, t = threadIdx.x;

    if (t < P) {
        float s = 0.f;
        for (int sp = 0; sp < nsplit; ++sp) s += s1p[((size_t)sp * BB + b) * P + t];
        mus[t] = s * (1.0f / MM);
    }
    __syncthreads();

    float tr_part = 0.f, s2_part = 0.f;
    #pragma unroll
    for (int j = 0; j < 16; ++j) {
        int f = t + 256 * j;
        int i = f >> 6, jc = f & 63;
        float sum = 0.f;
        for (int sp = 0; sp < nsplit; ++sp)
            sum += s2p[((size_t)sp * BB + b) * (P * P) + f];
        float v = sum * (1.0f / MM) - mus[i] * mus[jc];
        B0[i][jc] = v;
        s2_part += v * v;
        if (i == jc) tr_part += v;
    }
    #pragma unroll
    for (int off = 32; off > 0; off >>= 1) {
        tr_part += __shfl_down(tr_part, off);
        s2_part += __shfl_down(s2_part, off);
    }
    if ((t & 63) == 0) { red[0][t >> 6] = tr_part; red[1][t >> 6] = s2_part; }
    __syncthreads();
    const float trace = red[0][0] + red[0][1] + red[0][2] + red[0][3];
    const float sum2  = red[1][0] + red[1][1] + red[1][2] + red[1][3];

    const float nf = (float)MM;
    const float num = (nf - 2.0f) / nf * sum2 + trace * trace;
    const float den = (nf + 2.0f) * (sum2 - trace * trace / (float)P);
    const float rho = (den > 0.f) ? fminf(num / den, 1.0f) : 1.0f;
    const float lam = trace * (1.0f / P);
    const float inv_s = 1.0f / lam;

    #pragma unroll
    for (int j = 0; j < 16; ++j) {
        int f = t + 256 * j;
        int i = f >> 6, jc = f & 63;
        float v = B0[i][jc];
        float sv = ((1.0f - rho) * v + ((i == jc) ? rho * lam : 0.f)) * inv_s;
        B0[i][jc] = sv;
        B2[i][jc] = ((i == jc) ? 1.5f : 0.f) - 0.5f * sv;
    }

    // Newton-Schulz, 3 maps (spectrum in [0.73,1.27] -> error ~6e-6)
    mm64f(B1, B0, B2, t, 1.f, 0.f);          // map1: Y1=A*T1, Z1=T1
    Mat68 Yc = B1, Zc = B2, Tc = B0, U = B3, V = B4;
    {
        mm64f(Tc, Zc, Yc, t, -0.5f, 1.5f);   // map2
        mm64f(U,  Yc, Tc, t, 1.f, 0.f);
        mm64f(V,  Tc, Zc, t, 1.f, 0.f);
        Mat68 tmp = Yc; Yc = U; U = tmp;
        tmp = Zc; Zc = V; V = tmp;
    }
    mm64f(Tc, Zc, Yc, t, -0.5f, 1.5f);       // map3
    mm64f(U,  Tc, Zc, t, 1.f, 0.f);          // U = A^{-1/2}
    __syncthreads();

    const float sc = rsqrtf(lam);
    // S_hat emitted pair-packed: sb[dp*64 + row] = {bf16 S[row][2dp], bf16 S[row][2dp+1]}
    unsigned* sb = sbb + (size_t)b * (P * P / 2);
    #pragma unroll
    for (int j = 0; j < 8; ++j) {
        int slot = t + 256 * j;
        int dp = slot >> 6, row = slot & 63;
        sb[slot] = cvtpk(U[row][2 * dp] * sc, U[row][2 * dp + 1] * sc);
    }
    if (t < P) {
        float tv = 0.f;
        #pragma unroll
        for (int d = 0; d < P; ++d) tv += U[t][d] * mus[d];
        tvec[b * P + t] = tv * sc;
    }
}

// ---------------- Kernel C (xpk): Z = S_hat * x - t, reads pre-packed bf16 ----------------
__global__ __launch_bounds__(256)
void apply_kernel_x(const unsigned* __restrict__ xpk, const unsigned* __restrict__ sbb,
                    const float* __restrict__ tvec, float* __restrict__ out)
{
    __shared__ unsigned Spk[32][68];     // 8704 B
    __shared__ unsigned Xpk[32][260];    // 33280 B
    __shared__ float tvs[P];
    const int mt = blockIdx.x, b = blockIdx.y;
    const int t = threadIdx.x;
    const int w = t >> 6, l = t & 63;
    const int lr = l & 31, lh = l >> 5;

    const unsigned* sb = sbb + (size_t)b * (P * P / 2);
    #pragma unroll
    for (int j = 0; j < 8; ++j) {
        int slot = t + 256 * j;
        Spk[slot >> 6][slot & 63] = sb[slot];
    }
    if (t < P) tvs[t] = tvec[b * P + t];

    const unsigned* xb = xpk + (size_t)b * (32 * MM) + mt * MT;
    #pragma unroll
    for (int j = 0; j < 8; ++j) {
        int slot = t + 256 * j;
        int dp = slot >> 6, m0 = (slot & 63) * 4;
        u32x4 pk = *reinterpret_cast<const u32x4*>(xb + (size_t)dp * MM + m0);
        *reinterpret_cast<u32x4*>(&Xpk[dp][m0]) = pk;
    }
    __syncthreads();

    union U8 { unsigned u[4]; bf16x8 v; };
    bf16x8 sa0[4], sa1[4];
    #pragma unroll
    for (int ks = 0; ks < 4; ++ks) {
        const int dpb = ks * 8 + lh * 4;
        U8 x0, x1;
        #pragma unroll
        for (int q = 0; q < 4; ++q) {
            x0.u[q] = Spk[dpb + q][lr];
            x1.u[q] = Spk[dpb + q][32 + lr];
        }
        sa0[ks] = x0.v;
        sa1[ks] = x1.v;
    }

    f32x16 acc00 = {0,0,0,0,0,0,0,0,0,0,0,0,0,0,0,0};
    f32x16 acc01 = {0,0,0,0,0,0,0,0,0,0,0,0,0,0,0,0};
    f32x16 acc10 = {0,0,0,0,0,0,0,0,0,0,0,0,0,0,0,0};
    f32x16 acc11 = {0,0,0,0,0,0,0,0,0,0,0,0,0,0,0,0};

    const int cq0 = (2 * w) * 32 + lr, cq1 = cq0 + 32;
    #pragma unroll
    for (int ks = 0; ks < 4; ++ks) {
        const int dpb = ks * 8 + lh * 4;
        U8 b0, b1;
        #pragma unroll
        for (int q = 0; q < 4; ++q) {
            b0.u[q] = Xpk[dpb + q][cq0];
            b1.u[q] = Xpk[dpb + q][cq1];
        }
        acc00 = MF(sa0[ks], b0.v, acc00);
        acc01 = MF(sa0[ks], b1.v, acc01);
        acc10 = MF(sa1[ks], b0.v, acc10);
        acc11 = MF(sa1[ks], b1.v, acc11);
    }

    float* ob = out + (size_t)b * (P * MM) + mt * MT;
#define STORE_TILE(ACC, RT, CQ)                                          \
    {                                                                    \
        _Pragma("unroll")                                                \
        for (int n = 0; n < 16; ++n) {                                   \
            int row = (RT) * 32 + (n & 3) + 8 * (n >> 2) + 4 * lh;       \
            __builtin_nontemporal_store(ACC[n] - tvs[row],               \
                                        ob + (size_t)row * MM + (CQ));   \
        }                                                                \
    }
    STORE_TILE(acc00, 0, cq0)
    STORE_TILE(acc01, 0, cq1)
    STORE_TILE(acc10, 1, cq0)
    STORE_TILE(acc11, 1, cq1)
#undef STORE_TILE
}

// ---------------- Kernel C (legacy fallback): reads f32 x, converts in-kernel ----------------
__global__ __launch_bounds__(256)
void apply_kernel(const float* __restrict__ x, const unsigned* __restrict__ sbb,
                  const float* __restrict__ tvec, float* __restrict__ out)
{
    __shared__ unsigned Spk[32][68];
    __shared__ unsigned Xpk[32][260];
    __shared__ float tvs[P];
    const int mt = blockIdx.x, b = blockIdx.y;
    const int t = threadIdx.x;
    const int w = t >> 6, l = t & 63;
    const int lr = l & 31, lh = l >> 5;

    const unsigned* sb = sbb + (size_t)b * (P * P / 2);
    #pragma unroll
    for (int j = 0; j < 8; ++j) {
        int slot = t + 256 * j;
        Spk[slot >> 6][slot & 63] = sb[slot];
    }
    if (t < P) tvs[t] = tvec[b * P + t];

    const float* xb = x + (size_t)b * (P * MM) + mt * MT;
    #pragma unroll
    for (int j = 0; j < 8; ++j) {
        int slot = t + 256 * j;
        int dp = slot >> 6, m0 = (slot & 63) * 4;
        const float* xr = xb + (size_t)(2 * dp) * MM + m0;
        f32x4 a = *reinterpret_cast<const f32x4*>(xr);
        f32x4 c = *reinterpret_cast<const f32x4*>(xr + MM);
        uint4 pk = make_uint4(cvtpk(a.x, c.x), cvtpk(a.y, c.y),
                              cvtpk(a.z, c.z), cvtpk(a.w, c.w));
        *reinterpret_cast<uint4*>(&Xpk[dp][m0]) = pk;
    }
    __syncthreads();

    union U8 { unsigned u[4]; bf16x8 v; };
    bf16x8 sa0[4], sa1[4];
    #pragma unroll
    for (int ks = 0; ks < 4; ++ks) {
        const int dpb = ks * 8 + lh * 4;
        U8 x0, x1;
        #pragma unroll
        for (int q = 0; q < 4; ++q) {
            x0.u[q] = Spk[dpb + q][lr];
            x1.u[q] = Spk[dpb + q][32 + lr];
        }
        sa0[ks] = x0.v;
        sa1[ks] = x1.v;
    }

    f32x16 acc00 = {0,0,0,0,0,0,0,0,0,0,0,0,0,0,0,0};
    f32x16 acc01 = {0,0,0,0,0,0,0,0,0,0,0,0,0,0,0,0};
    f32x16 acc10 = {0,0,0,0,0,0,0,0,0,0,0,0,0,0,0,0};
    f32x16 acc11 = {0,0,0,0,0,0,0,0,0,0,0,0,0,0,0,0};

    const int cq0 = (2 * w) * 32 + lr, cq1 = cq0 + 32;
    #pragma unroll
    for (int ks = 0; ks < 4; ++ks) {
        const int dpb = ks * 8 + lh * 4;
        U8 b0, b1;
        #pragma unroll
        for (int q = 0; q < 4; ++q) {
            b0.u[q] = Xpk[dpb + q][cq0];
            b1.u[q] = Xpk[dpb + q][cq1];
        }
        acc00 = MF(sa0[ks], b0.v, acc00);
        acc01 = MF(sa0[ks], b1.v, acc01);
        acc10 = MF(sa1[ks], b0.v, acc10);
        acc11 = MF(sa1[ks], b1.v, acc11);
    }

    float* ob = out + (size_t)b * (P * MM) + mt * MT;
#define STORE_TILE(ACC, RT, CQ)                                          \
    {                                                                    \
        _Pragma("unroll")                                                \
        for (int n = 0; n < 16; ++n) {                                   \
            int row = (RT) * 32 + (n & 3) + 8 * (n >> 2) + 4 * lh;       \
            __builtin_nontemporal_store(ACC[n] - tvs[row],               \
                                        ob + (size_t)row * MM + (CQ));   \
        }                                                                \
    }
    STORE_TILE(acc00, 0, cq0)
    STORE_TILE(acc01, 0, cq1)
    STORE_TILE(acc10, 1, cq0)
    STORE_TILE(acc11, 1, cq1)
#undef STORE_TILE
}

extern "C" void kernel_launch(void* const* d_in, const int* in_sizes, int n_in,
                              void* d_out, int out_size, void* d_ws, size_t ws_size,
                              hipStream_t stream)
{
    const float* x = (const float*)d_in[0];
    float* out = (float*)d_out;

    // scratch: s2p[ns][B][64][64] f32 | s1p[ns][B][64] f32 |
    // sbb[B][32][64] uint | tvec[B][64] f32 | xpk[B][32][4096] uint (optional)
    auto need = [](int ns) -> size_t {
        return ((size_t)ns * BB * P * P + (size_t)ns * BB * P
                + (size_t)BB * P * P / 2 + (size_t)BB * P) * sizeof(float);
    };
    const size_t xpk_bytes = (size_t)BB * 32 * MM * sizeof(unsigned);   // 134 MB

    int nsplit;
    bool xon;
    if (ws_size >= need(4) + xpk_bytes)      { nsplit = 4; xon = true; }
    else if (ws_size >= need(2) + xpk_bytes) { nsplit = 2; xon = true; }
    else {
        xon = false;
        nsplit = (ws_size >= need(4)) ? 4 : (ws_size >= need(2)) ? 2 : 1;
    }

    float* s2p  = (float*)d_ws;
    float* s1p  = s2p + (size_t)nsplit * BB * P * P;
    unsigned* sbb = (unsigned*)(s1p + (size_t)nsplit * BB * P);
    float* tvec = (float*)(sbb + (size_t)BB * P * P / 2);
    unsigned* xpk = (unsigned*)(tvec + (size_t)BB * P);

    if (xon) {
        covpart_kernel<true><<<dim3(BB, nsplit), 256, 0, stream>>>(x, s2p, s1p, xpk, nsplit);
        whiten_kernel<<<dim3(BB), 256, 0, stream>>>(s2p, s1p, sbb, tvec, nsplit);
        apply_kernel_x<<<dim3(MM / MT, BB), 256, 0, stream>>>(xpk, sbb, tvec, out);
    } else {
        covpart_kernel<false><<<dim3(BB, nsplit), 256, 0, stream>>>(x, s2p, s1p, nullptr, nsplit);
        whiten_kernel<<<dim3(BB), 256, 0, stream>>>(s2p, s1p, sbb, tvec, nsplit);
        apply_kernel<<<dim3(MM / MT, BB), 256, 0, stream>>>(x, sbb, tvec, out);
    }
}